// Round 11
// baseline (106.938 us; speedup 1.0000x reference)
//
#include <hip/hip_runtime.h>

#define PL 128
#define STRIDE 64
#define WSZ 16

typedef float f32x4 __attribute__((ext_vector_type(4)));

// R10 structure (grid 256 = 1 block/CU, lockstep sweep, nt stores), single
// variable changed: per-wave BURST length 1 KB -> 8 KB. Each wave writes 8
// consecutive 1 KB lines per iteration (8 stores at +64 f32x4 offsets);
// device window per iteration grows 1 MB -> 8 MB.
//
// Invariance: T = 256 blocks * 2048 f32x4 = 524288 ≡ 0 (mod 4096 = patch
// size), so within-patch offset q = (bid*2048 + w*512 + u*64 + l) & 4095
// is loop-invariant. Row of v[u] = (bid&1)*64 + w*16 + u*2 + (l>>5),
// col = (l&31)*4 + c  — all indices static, 8 f32x4 registers.
__global__ __launch_bounds__(256) void fused_kernel(
    const float* __restrict__ I, const float* __restrict__ Q,
    const float* __restrict__ ew, float* __restrict__ out, int P)
{
    const int tid = threadIdx.x;
    const int bid = blockIdx.x;

    // ---- Part A: patches [P,128,2] (8 MB) — unchanged from R10 ----
    {
        const unsigned TA   = gridDim.x * 256u;
        const unsigned idx0 = bid * 256u + tid;
        f32x4* pout = reinterpret_cast<f32x4*>(out);
        const unsigned total = (unsigned)P * (PL / 2);   // f32x4 covers t,t+1
        for (unsigned idx = idx0; idx < total; idx += TA) {
            int p = (int)(idx >> 6);
            int t = ((int)idx & 63) * 2;
            int src = p * STRIDE + t;
            f32x4 val = {I[src], Q[src], I[src + 1], Q[src + 1]};
            pout[idx] = val;
        }
    }

    // ---- Part B: 8 f32x4 adj registers for this thread's burst slots ----
    const int w = tid >> 6;          // wave 0..3
    const int l = tid & 63;          // lane
    const int rbase = (bid & 1) * 64 + w * 16 + (l >> 5);
    const int j0    = (l & 31) * 4;
    f32x4 v[8];
#pragma unroll
    for (int u = 0; u < 8; ++u) {
        const int row = rbase + u * 2;
        f32x4 val = {0.f, 0.f, 0.f, 0.f};
#pragma unroll
        for (int c = 0; c < 4; ++c) {
            int j = j0 + c;
            int d = row - j; if (d < 0) d = -d;
            if (d > 0 && d <= WSZ) {
                val[c] = 1.0f / (1.0f + __expf(-ew[row * PL + j]));
            }
        }
        v[u] = val;
    }

    // ---- Part C: lockstep sweep, 8 KB contiguous burst per wave per iter ----
    f32x4* aout = reinterpret_cast<f32x4*>(out + (size_t)P * PL * 2);
    const unsigned M = (unsigned)P * (PL * PL / 4);      // 31,993,856 (mult of 512)
    const unsigned T = gridDim.x * 2048u;                // 524288 f32x4 = 8 MB
    for (unsigned m = bid * 2048u + w * 512u + l; m < M; m += T) {
#pragma unroll
        for (int u = 0; u < 8; ++u) {
            __builtin_nontemporal_store(v[u], &aout[m + u * 64]);
        }
    }
}

extern "C" void kernel_launch(void* const* d_in, const int* in_sizes, int n_in,
                              void* d_out, int out_size, void* d_ws, size_t ws_size,
                              hipStream_t stream) {
    const float* I  = (const float*)d_in[0];
    const float* Q  = (const float*)d_in[1];
    const float* ew = (const float*)d_in[2];
    float* out = (float*)d_out;

    const int n = in_sizes[0];
    const int P = (n - PL) / STRIDE + 1;   // 7811 for L=500000

    // 256 blocks = 1 per CU; even count keeps the (bid&1) half-matrix mapping.
    fused_kernel<<<256, 256, 0, stream>>>(I, Q, ew, out, P);
}

// Round 12
// 98.531 us; speedup vs baseline: 1.0853x; 1.0853x over previous
//
#include <hip/hip_runtime.h>

#define PL 128
#define STRIDE 64
#define WSZ 16

typedef float f32x4 __attribute__((ext_vector_type(4)));

// R10 structure (lockstep sweep, one invariant f32x4 per thread, nt stores),
// single variable changed: grid 256 -> 512 (2 blocks/CU, 8 waves/CU, 2 MB
// window). Tests the occupancy x nt interaction: R9's 512-block regression
// was with NORMAL stores (L2 evict-path thrash); with nt the L2 is bypassed,
// so extra waves should add pure store-MLP per CU.
__global__ __launch_bounds__(256) void fused_kernel(
    const float* __restrict__ I, const float* __restrict__ Q,
    const float* __restrict__ ew, float* __restrict__ out, int P)
{
    const int tid = threadIdx.x;
    const int bid = blockIdx.x;
    const unsigned T    = gridDim.x * 256u;     // f32x4 grid stride
    const unsigned idx0 = bid * 256u + tid;

    // ---- Part A: patches [P,128,2] (8 MB) ----
    {
        f32x4* pout = reinterpret_cast<f32x4*>(out);
        const unsigned total = (unsigned)P * (PL / 2);   // f32x4 covers t,t+1
        for (unsigned idx = idx0; idx < total; idx += T) {
            int p = (int)(idx >> 6);
            int t = ((int)idx & 63) * 2;
            int src = p * STRIDE + t;
            f32x4 val = {I[src], Q[src], I[src + 1], Q[src + 1]};
            pout[idx] = val;
        }
    }

    // ---- Part B: this thread's single f32x4 of adj ----
    // element e = (kk*256 + tid)*4 + c -> row = kk*8 + (tid>>5), col = (tid&31)*4 + c
    const int kk  = bid & 15;
    const int row = kk * 8 + (tid >> 5);
    const int j0  = (tid & 31) * 4;
    f32x4 v = {0.f, 0.f, 0.f, 0.f};
#pragma unroll
    for (int c = 0; c < 4; ++c) {
        int j = j0 + c;
        int d = row - j; if (d < 0) d = -d;
        if (d > 0 && d <= WSZ) {
            v[c] = 1.0f / (1.0f + __expf(-ew[row * PL + j]));
        }
    }

    // ---- Part C: lockstep sweep, nontemporal stores ----
    f32x4* aout = reinterpret_cast<f32x4*>(out + (size_t)P * PL * 2);
    const unsigned M = (unsigned)P * (PL * PL / 4);      // 31,993,856 for P=7811
    for (unsigned m = idx0; m < M; m += T) {
        __builtin_nontemporal_store(v, &aout[m]);
    }
}

extern "C" void kernel_launch(void* const* d_in, const int* in_sizes, int n_in,
                              void* d_out, int out_size, void* d_ws, size_t ws_size,
                              hipStream_t stream) {
    const float* I  = (const float*)d_in[0];
    const float* Q  = (const float*)d_in[1];
    const float* ew = (const float*)d_in[2];
    float* out = (float*)d_out;

    const int n = in_sizes[0];
    const int P = (n - PL) / STRIDE + 1;   // 7811 for L=500000

    // 512 blocks = 2 per CU (8 waves/CU); multiple of 16 keeps the
    // invariant-offset mapping exact.
    fused_kernel<<<512, 256, 0, stream>>>(I, Q, ew, out, P);
}

// Round 13
// 95.604 us; speedup vs baseline: 1.1186x; 1.0306x over previous
//
#include <hip/hip_runtime.h>

#define PL 128
#define STRIDE 64
#define WSZ 16

typedef float f32x4 __attribute__((ext_vector_type(4)));

// WINNER (R10 configuration, best of all axes swept R1-R12):
//   grid 256 = 1 block/CU, device-lockstep 1 MB sweep window,
//   one loop-invariant f32x4 register per thread, nontemporal stores.
// 95.5 us ~= 5.8 TB/s effective; ~84% of the co-measured fillBufferAligned
// write rate. Axes exonerated single-variable: address pattern (x5),
// dispatch fusion, window size (1/2/8 MB), waves/CU (4/8 +-nt), burst
// length (1/8 KB), L2 policy (nt wins), fixed overhead (~2 us).
__global__ __launch_bounds__(256) void fused_kernel(
    const float* __restrict__ I, const float* __restrict__ Q,
    const float* __restrict__ ew, float* __restrict__ out, int P)
{
    const int tid = threadIdx.x;
    const int bid = blockIdx.x;
    const unsigned T    = gridDim.x * 256u;     // 65536 f32x4 = 1 MB window
    const unsigned idx0 = bid * 256u + tid;

    // ---- Part A: patches [P,128,2] (8 MB) ----
    {
        f32x4* pout = reinterpret_cast<f32x4*>(out);
        const unsigned total = (unsigned)P * (PL / 2);   // f32x4 covers t,t+1
        for (unsigned idx = idx0; idx < total; idx += T) {
            int p = (int)(idx >> 6);
            int t = ((int)idx & 63) * 2;
            int src = p * STRIDE + t;
            f32x4 val = {I[src], Q[src], I[src + 1], Q[src + 1]};
            pout[idx] = val;
        }
    }

    // ---- Part B: this thread's single f32x4 of adj ----
    // element e = (kk*256 + tid)*4 + c -> row = kk*8 + (tid>>5), col = (tid&31)*4 + c
    const int kk  = bid & 15;
    const int row = kk * 8 + (tid >> 5);
    const int j0  = (tid & 31) * 4;
    f32x4 v = {0.f, 0.f, 0.f, 0.f};
#pragma unroll
    for (int c = 0; c < 4; ++c) {
        int j = j0 + c;
        int d = row - j; if (d < 0) d = -d;
        if (d > 0 && d <= WSZ) {
            v[c] = 1.0f / (1.0f + __expf(-ew[row * PL + j]));
        }
    }

    // ---- Part C: device-lockstep sweep, nontemporal stores ----
    f32x4* aout = reinterpret_cast<f32x4*>(out + (size_t)P * PL * 2);
    const unsigned M = (unsigned)P * (PL * PL / 4);      // 31,993,856 for P=7811
    for (unsigned m = idx0; m < M; m += T) {
        __builtin_nontemporal_store(v, &aout[m]);
    }
}

extern "C" void kernel_launch(void* const* d_in, const int* in_sizes, int n_in,
                              void* d_out, int out_size, void* d_ws, size_t ws_size,
                              hipStream_t stream) {
    const float* I  = (const float*)d_in[0];
    const float* Q  = (const float*)d_in[1];
    const float* ew = (const float*)d_in[2];
    float* out = (float*)d_out;

    const int n = in_sizes[0];
    const int P = (n - PL) / STRIDE + 1;   // 7811 for L=500000

    // 256 blocks = 1 per CU; multiple of 16 keeps the invariant-offset mapping.
    fused_kernel<<<256, 256, 0, stream>>>(I, Q, ew, out, P);
}